// Round 3
// baseline (1520.155 us; speedup 1.0000x reference)
//
#include <hip/hip_runtime.h>
#include <hip/hip_bf16.h>
#include <math.h>

constexpr int kB   = 2;
constexpr int kS   = 1024;
constexpr int kD   = 1024;
constexpr int kH   = 16;
constexpr int kDH  = 64;
constexpr int kHID = 2048;
constexpr int kE   = 8;
constexpr int kTok = kB * kS;         // 2048
constexpr float kScale = 0.125f;
constexpr long long kOutLogits = (long long)kTok * kD;
constexpr long long kOutProbs  = kOutLogits + kE * kB;

using u16 = unsigned short;
typedef __attribute__((ext_vector_type(8))) short short8;
typedef __attribute__((ext_vector_type(4))) float f32x4;

__device__ __forceinline__ float b2f(u16 u) {
  union { unsigned int i; float f; } c; c.i = ((unsigned int)u) << 16; return c.f;
}
__device__ __forceinline__ u16 f2b(float f) {
  __hip_bfloat16 h = __float2bfloat16(f);
  u16 u; __builtin_memcpy(&u, &h, 2); return u;
}
__device__ __forceinline__ float ldIn(const void* p, long long i, int f32) {
  return f32 ? ((const float*)p)[i] : b2f(((const u16*)p)[i]);
}
// load 8 consecutive elements of an input tensor as fp32
__device__ __forceinline__ void ld8f(const void* p, long long i, int f32, float v[8]) {
  if (f32) {
    const float* fp = (const float*)p + i;
    float4 a = *(const float4*)fp, b = *(const float4*)(fp + 4);
    v[0]=a.x; v[1]=a.y; v[2]=a.z; v[3]=a.w; v[4]=b.x; v[5]=b.y; v[6]=b.z; v[7]=b.w;
  } else {
    short8 s = *(const short8*)((const u16*)p + i);
#pragma unroll
    for (int j = 0; j < 8; j++) v[j] = b2f((u16)s[j]);
  }
}
__device__ __forceinline__ void stOut(void* base, long long i, float v, int f32) {
  if (f32) ((float*)base)[i] = v; else ((u16*)base)[i] = f2b(v);
}

__device__ __forceinline__ float blockReduceSum(float v) {
  __shared__ float sh[4];
  int lane = threadIdx.x & 63, wv = threadIdx.x >> 6;
#pragma unroll
  for (int o = 32; o; o >>= 1) v += __shfl_down(v, o, 64);
  __syncthreads();
  if (lane == 0) sh[wv] = v;
  __syncthreads();
  return sh[0] + sh[1] + sh[2] + sh[3];
}
__device__ __forceinline__ float blockReduceMax(float v) {
  __shared__ float sh[4];
  int lane = threadIdx.x & 63, wv = threadIdx.x >> 6;
#pragma unroll
  for (int o = 32; o; o >>= 1) v = fmaxf(v, __shfl_down(v, o, 64));
  __syncthreads();
  if (lane == 0) sh[wv] = v;
  __syncthreads();
  return fmaxf(fmaxf(sh[0], sh[1]), fmaxf(sh[2], sh[3]));
}

// ------------------------------------------------------------- detect -------
__global__ void detect_k(const void* x, int* dflag) {
  __shared__ int sg, st;
  int tid = threadIdx.x;
  if (tid == 0) { sg = 0; st = 0; }
  __syncthreads();
  const unsigned int* w = (const unsigned int*)x;
  int good = 0, tot = 0;
  for (int i = tid; i < 1024; i += 256) {
    unsigned int lo = w[i] & 0xffffu;
    if (lo) {
      tot++;
      unsigned int e = (lo >> 7) & 0xffu;
      if (e >= 97 && e <= 159) good++;
    }
  }
  atomicAdd(&sg, good); atomicAdd(&st, tot);
  __syncthreads();
  if (tid == 0) dflag[0] = (sg * 10 < st * 9) ? 1 : 0;
}

// --------------------------------------- high-precision split-bf16 GEMM -----
// C[M,N] (fp32) = A[M,K] @ B, inputs split into hi+lo bf16; 4 MFMA terms
// give fp32-comparable accuracy (rel err ~4e-6).
// aF/bF: 1 = true input (dtype per dflag), 2 = fp32 intermediate.
struct G3P {
  const void* A; const void* Bm; float* C;
  long long a0, a1, b0, b1, c0, c1;
  int zdiv, zA, zB, zC;
  int lda, ldb, ldc, M, N, K;
  int bT, aF, bF;
  const int* dflag;
  const void* bias;
};

__global__ __launch_bounds__(256) void gemm3_k(G3P p) {
  const int z = blockIdx.z;
  const int m0 = blockIdx.y * 64, n0 = blockIdx.x * 64;
  const int f32in = p.dflag[0];
  const int af32 = (p.aF == 2) || (p.aF == 1 && f32in);
  const int bf32 = (p.bF == 2) || (p.bF == 1 && f32in);
  const int gA = z + p.zA, gB = z + p.zB, gC = z + p.zC;
  const long long aoff = (long long)(gA / p.zdiv) * p.a0 + (long long)(gA % p.zdiv) * p.a1;
  const long long boff = (long long)(gB / p.zdiv) * p.b0 + (long long)(gB % p.zdiv) * p.b1;
  const long long coff = (long long)(gC / p.zdiv) * p.c0 + (long long)(gC % p.zdiv) * p.c1;

  __shared__ short Ah[64][32], Al[64][32], Bh[64][32], Bl[64][32];

  const int tid = threadIdx.x;
  const int wave = tid >> 6, lane = tid & 63;
  const int wr = wave >> 1, wc = wave & 1;
  const int quad = lane >> 4, l16 = lane & 15;

  const int arow = tid >> 2, ak = (tid & 3) * 8;
  const long long abase = aoff + (long long)(m0 + arow) * p.lda + ak;
  const int btrow = tid >> 2, btk = (tid & 3) * 8;   // bT=1
  const int bkk = tid >> 3, bnn = (tid & 7) * 8;     // bT=0

  f32x4 acc[2][2];
  const f32x4 z4 = {0.f, 0.f, 0.f, 0.f};
  acc[0][0] = z4; acc[0][1] = z4; acc[1][0] = z4; acc[1][1] = z4;

  for (int k0 = 0; k0 < p.K; k0 += 32) {
    float va[8];
    ld8f(p.A, abase + k0, af32, va);
#pragma unroll
    for (int j = 0; j < 8; j++) {
      u16 h = f2b(va[j]);
      Ah[arow][ak + j] = (short)h;
      Al[arow][ak + j] = (short)f2b(va[j] - b2f(h));
    }
    float vb[8];
    if (p.bT) {
      ld8f(p.Bm, boff + (long long)(n0 + btrow) * p.ldb + k0 + btk, bf32, vb);
#pragma unroll
      for (int j = 0; j < 8; j++) {
        u16 h = f2b(vb[j]);
        Bh[btrow][btk + j] = (short)h;
        Bl[btrow][btk + j] = (short)f2b(vb[j] - b2f(h));
      }
    } else {
      ld8f(p.Bm, boff + (long long)(k0 + bkk) * p.ldb + n0 + bnn, bf32, vb);
#pragma unroll
      for (int j = 0; j < 8; j++) {
        u16 h = f2b(vb[j]);
        Bh[bnn + j][bkk] = (short)h;
        Bl[bnn + j][bkk] = (short)f2b(vb[j] - b2f(h));
      }
    }
    __syncthreads();
    short8 ah0 = *(const short8*)(&Ah[wr * 32 + l16][quad * 8]);
    short8 ah1 = *(const short8*)(&Ah[wr * 32 + 16 + l16][quad * 8]);
    short8 al0 = *(const short8*)(&Al[wr * 32 + l16][quad * 8]);
    short8 al1 = *(const short8*)(&Al[wr * 32 + 16 + l16][quad * 8]);
    short8 bh0 = *(const short8*)(&Bh[wc * 32 + l16][quad * 8]);
    short8 bh1 = *(const short8*)(&Bh[wc * 32 + 16 + l16][quad * 8]);
    short8 bl0 = *(const short8*)(&Bl[wc * 32 + l16][quad * 8]);
    short8 bl1 = *(const short8*)(&Bl[wc * 32 + 16 + l16][quad * 8]);
    // ll + lh + hl + hh (small terms first)
    acc[0][0] = __builtin_amdgcn_mfma_f32_16x16x32_bf16(al0, bl0, acc[0][0], 0, 0, 0);
    acc[0][1] = __builtin_amdgcn_mfma_f32_16x16x32_bf16(al0, bl1, acc[0][1], 0, 0, 0);
    acc[1][0] = __builtin_amdgcn_mfma_f32_16x16x32_bf16(al1, bl0, acc[1][0], 0, 0, 0);
    acc[1][1] = __builtin_amdgcn_mfma_f32_16x16x32_bf16(al1, bl1, acc[1][1], 0, 0, 0);
    acc[0][0] = __builtin_amdgcn_mfma_f32_16x16x32_bf16(al0, bh0, acc[0][0], 0, 0, 0);
    acc[0][1] = __builtin_amdgcn_mfma_f32_16x16x32_bf16(al0, bh1, acc[0][1], 0, 0, 0);
    acc[1][0] = __builtin_amdgcn_mfma_f32_16x16x32_bf16(al1, bh0, acc[1][0], 0, 0, 0);
    acc[1][1] = __builtin_amdgcn_mfma_f32_16x16x32_bf16(al1, bh1, acc[1][1], 0, 0, 0);
    acc[0][0] = __builtin_amdgcn_mfma_f32_16x16x32_bf16(ah0, bl0, acc[0][0], 0, 0, 0);
    acc[0][1] = __builtin_amdgcn_mfma_f32_16x16x32_bf16(ah0, bl1, acc[0][1], 0, 0, 0);
    acc[1][0] = __builtin_amdgcn_mfma_f32_16x16x32_bf16(ah1, bl0, acc[1][0], 0, 0, 0);
    acc[1][1] = __builtin_amdgcn_mfma_f32_16x16x32_bf16(ah1, bl1, acc[1][1], 0, 0, 0);
    acc[0][0] = __builtin_amdgcn_mfma_f32_16x16x32_bf16(ah0, bh0, acc[0][0], 0, 0, 0);
    acc[0][1] = __builtin_amdgcn_mfma_f32_16x16x32_bf16(ah0, bh1, acc[0][1], 0, 0, 0);
    acc[1][0] = __builtin_amdgcn_mfma_f32_16x16x32_bf16(ah1, bh0, acc[1][0], 0, 0, 0);
    acc[1][1] = __builtin_amdgcn_mfma_f32_16x16x32_bf16(ah1, bh1, acc[1][1], 0, 0, 0);
    __syncthreads();
  }

#pragma unroll
  for (int sm = 0; sm < 2; sm++) {
#pragma unroll
    for (int r = 0; r < 4; r++) {
      int row = m0 + wr * 32 + sm * 16 + quad * 4 + r;
#pragma unroll
      for (int sn = 0; sn < 2; sn++) {
        int col = n0 + wc * 32 + sn * 16 + l16;
        float v = acc[sm][sn][r];
        if (p.bias) v += ldIn(p.bias, col, f32in);
        p.C[coff + (long long)row * p.ldc + col] = v;
      }
    }
  }
}

// -------------------------------------------- fused MoE W1/W3 + SwiGLU ------
__global__ __launch_bounds__(256) void moe13_k(const float* Xf, const void* W1, const void* W3,
                                               const int* counts, const int* offsets,
                                               const int* aidxArr, u16* Hbuf, const int* dflag) {
  int e = blockIdx.z;
  int Meff = counts[e];
  int m0 = blockIdx.y * 64;
  if (m0 >= Meff) return;
  int n0 = blockIdx.x * 64;
  int csr = offsets[e];
  const int wf32 = dflag[0];
  const long long ebase = (long long)e * kD * kHID;
  __shared__ short As[64][32], B1s[64][32], B3s[64][32];
  int tid = threadIdx.x, wave = tid >> 6, lane = tid & 63;
  int wr = wave >> 1, wc = wave & 1, quad = lane >> 4, l16 = lane & 15;
  int arow = tid >> 2, ak = (tid & 3) * 8;
  int grow = m0 + arow; if (grow >= Meff) grow = Meff - 1;
  const float* Aptr = Xf + (long long)aidxArr[csr + grow] * kD + ak;
  int bkk = tid >> 3, bnn = (tid & 7) * 8;
  f32x4 acc1[2][2], acc3[2][2];
  const f32x4 z4 = {0.f, 0.f, 0.f, 0.f};
  acc1[0][0] = z4; acc1[0][1] = z4; acc1[1][0] = z4; acc1[1][1] = z4;
  acc3[0][0] = z4; acc3[0][1] = z4; acc3[1][0] = z4; acc3[1][1] = z4;

  for (int k0 = 0; k0 < kD; k0 += 32) {
    float4 a0v = *(const float4*)(Aptr + k0);
    float4 a1v = *(const float4*)(Aptr + k0 + 4);
    As[arow][ak+0] = (short)f2b(a0v.x); As[arow][ak+1] = (short)f2b(a0v.y);
    As[arow][ak+2] = (short)f2b(a0v.z); As[arow][ak+3] = (short)f2b(a0v.w);
    As[arow][ak+4] = (short)f2b(a1v.x); As[arow][ak+5] = (short)f2b(a1v.y);
    As[arow][ak+6] = (short)f2b(a1v.z); As[arow][ak+7] = (short)f2b(a1v.w);
    long long bidx = ebase + (long long)(k0 + bkk) * kHID + n0 + bnn;
    float b1v[8], b3v[8];
    ld8f(W1, bidx, wf32, b1v);
    ld8f(W3, bidx, wf32, b3v);
#pragma unroll
    for (int i = 0; i < 8; i++) { B1s[bnn + i][bkk] = (short)f2b(b1v[i]); B3s[bnn + i][bkk] = (short)f2b(b3v[i]); }
    __syncthreads();
    short8 af0 = *(const short8*)(&As[wr * 32 + l16][quad * 8]);
    short8 af1 = *(const short8*)(&As[wr * 32 + 16 + l16][quad * 8]);
    short8 c10 = *(const short8*)(&B1s[wc * 32 + l16][quad * 8]);
    short8 c11 = *(const short8*)(&B1s[wc * 32 + 16 + l16][quad * 8]);
    short8 c30 = *(const short8*)(&B3s[wc * 32 + l16][quad * 8]);
    short8 c31 = *(const short8*)(&B3s[wc * 32 + 16 + l16][quad * 8]);
    acc1[0][0] = __builtin_amdgcn_mfma_f32_16x16x32_bf16(af0, c10, acc1[0][0], 0, 0, 0);
    acc1[0][1] = __builtin_amdgcn_mfma_f32_16x16x32_bf16(af0, c11, acc1[0][1], 0, 0, 0);
    acc1[1][0] = __builtin_amdgcn_mfma_f32_16x16x32_bf16(af1, c10, acc1[1][0], 0, 0, 0);
    acc1[1][1] = __builtin_amdgcn_mfma_f32_16x16x32_bf16(af1, c11, acc1[1][1], 0, 0, 0);
    acc3[0][0] = __builtin_amdgcn_mfma_f32_16x16x32_bf16(af0, c30, acc3[0][0], 0, 0, 0);
    acc3[0][1] = __builtin_amdgcn_mfma_f32_16x16x32_bf16(af0, c31, acc3[0][1], 0, 0, 0);
    acc3[1][0] = __builtin_amdgcn_mfma_f32_16x16x32_bf16(af1, c30, acc3[1][0], 0, 0, 0);
    acc3[1][1] = __builtin_amdgcn_mfma_f32_16x16x32_bf16(af1, c31, acc3[1][1], 0, 0, 0);
    __syncthreads();
  }
#pragma unroll
  for (int sm = 0; sm < 2; sm++) {
#pragma unroll
    for (int r = 0; r < 4; r++) {
      int row = m0 + wr * 32 + sm * 16 + quad * 4 + r;
      if (row >= Meff) continue;
#pragma unroll
      for (int sn = 0; sn < 2; sn++) {
        int col = n0 + wc * 32 + sn * 16 + l16;
        float g1 = acc1[sm][sn][r], g3 = acc3[sm][sn][r];
        float h = (g1 / (1.f + __expf(-g1))) * g3;
        Hbuf[(long long)(csr + row) * kHID + col] = f2b(h);
      }
    }
  }
}

// ------------------------------------------------ MoE W2 + scatter ---------
__global__ __launch_bounds__(256) void w2_k(const u16* Hbuf, const void* W2,
                                            const int* counts, const int* offsets,
                                            const int* aidxArr, const int* slotArr,
                                            const float* wgtArr, float* contrib,
                                            const int* dflag) {
  int e = blockIdx.z;
  int Meff = counts[e];
  int m0 = blockIdx.y * 64;
  if (m0 >= Meff) return;
  int n0 = blockIdx.x * 64;
  int csr = offsets[e];
  const int wf32 = dflag[0];
  const long long ebase = (long long)e * kHID * kD;
  __shared__ short As[64][32], Bs[64][32];
  int tid = threadIdx.x, wave = tid >> 6, lane = tid & 63;
  int wr = wave >> 1, wc = wave & 1, quad = lane >> 4, l16 = lane & 15;
  int arow = tid >> 2, ak = (tid & 3) * 8;
  int grow = m0 + arow; if (grow >= Meff) grow = Meff - 1;
  const u16* Aptr = Hbuf + (long long)(csr + grow) * kHID + ak;
  int bkk = tid >> 3, bnn = (tid & 7) * 8;
  f32x4 acc[2][2];
  const f32x4 z4 = {0.f, 0.f, 0.f, 0.f};
  acc[0][0] = z4; acc[0][1] = z4; acc[1][0] = z4; acc[1][1] = z4;

  for (int k0 = 0; k0 < kHID; k0 += 32) {
    *(short8*)(&As[arow][ak]) = *(const short8*)(Aptr + k0);
    float bv[8];
    ld8f(W2, ebase + (long long)(k0 + bkk) * kD + n0 + bnn, wf32, bv);
#pragma unroll
    for (int i = 0; i < 8; i++) Bs[bnn + i][bkk] = (short)f2b(bv[i]);
    __syncthreads();
    short8 af0 = *(const short8*)(&As[wr * 32 + l16][quad * 8]);
    short8 af1 = *(const short8*)(&As[wr * 32 + 16 + l16][quad * 8]);
    short8 bf0 = *(const short8*)(&Bs[wc * 32 + l16][quad * 8]);
    short8 bf1 = *(const short8*)(&Bs[wc * 32 + 16 + l16][quad * 8]);
    acc[0][0] = __builtin_amdgcn_mfma_f32_16x16x32_bf16(af0, bf0, acc[0][0], 0, 0, 0);
    acc[0][1] = __builtin_amdgcn_mfma_f32_16x16x32_bf16(af0, bf1, acc[0][1], 0, 0, 0);
    acc[1][0] = __builtin_amdgcn_mfma_f32_16x16x32_bf16(af1, bf0, acc[1][0], 0, 0, 0);
    acc[1][1] = __builtin_amdgcn_mfma_f32_16x16x32_bf16(af1, bf1, acc[1][1], 0, 0, 0);
    __syncthreads();
  }
#pragma unroll
  for (int sm = 0; sm < 2; sm++) {
#pragma unroll
    for (int r = 0; r < 4; r++) {
      int row = m0 + wr * 32 + sm * 16 + quad * 4 + r;
      if (row >= Meff) continue;
      int a = csr + row;
      int t = aidxArr[a]; int s = slotArr[a]; float w = wgtArr[a];
#pragma unroll
      for (int sn = 0; sn < 2; sn++) {
        int col = n0 + wc * 32 + sn * 16 + l16;
        contrib[((long long)s * kTok + t) * kD + col] = acc[sm][sn][r] * w;
      }
    }
  }
}

// ------------------------------------------------------------ small ops -----
__global__ void maskprep_k(const void* srcm, const void* tgtm, const void* midm,
                           float* srcf, float* padf, float* keepf, float* denom) {
  __shared__ int okInt, okFloat, okBf16;
  int tid = threadIdx.x;
  if (tid == 0) { okInt = 1; okFloat = 1; okBf16 = 1; }
  __syncthreads();
  const unsigned int* wi = (const unsigned int*)tgtm;
  const float* wf = (const float*)tgtm;
  int badI = 0, badF = 0, badB = 0;
  for (int i = tid; i < 512; i += 256) {
    unsigned int w = wi[i];
    if (w > 1u) badI = 1;
    float f = wf[i];
    if (!(f == 0.f || f == 1.f)) badF = 1;
    unsigned int lo = w & 0xffffu, hi = w >> 16;
    if (!((lo == 0 || lo == 0x3f80u) && (hi == 0 || hi == 0x3f80u))) badB = 1;
  }
  if (badI) atomicExch(&okInt, 0);
  if (badF) atomicExch(&okFloat, 0);
  if (badB) atomicExch(&okBf16, 0);
  __syncthreads();
  int mode = okInt ? 0 : (okFloat ? 2 : (okBf16 ? 3 : 1));
  for (int i = tid; i < kTok; i += 256) {
    bool sv, pv, mv;
    if (mode == 0) {
      sv = ((const int*)srcm)[i] != 0; pv = ((const int*)tgtm)[i] != 0; mv = ((const int*)midm)[i] != 0;
    } else if (mode == 2) {
      sv = ((const float*)srcm)[i] != 0.f; pv = ((const float*)tgtm)[i] != 0.f; mv = ((const float*)midm)[i] != 0.f;
    } else if (mode == 3) {
      sv = ((const u16*)srcm)[i] != 0; pv = ((const u16*)tgtm)[i] != 0; mv = ((const u16*)midm)[i] != 0;
    } else {
      sv = ((const unsigned char*)srcm)[i] != 0; pv = ((const unsigned char*)tgtm)[i] != 0; mv = ((const unsigned char*)midm)[i] != 0;
    }
    srcf[i] = sv ? 1.f : 0.f;
    padf[i] = pv ? 1.f : 0.f;
    keepf[i] = (pv || mv) ? 0.f : 1.f;
  }
  __syncthreads();
  if (tid < 2) {
    float s = 0;
    for (int j = 0; j < kS; j++) s += keepf[tid * kS + j];
    denom[tid] = fmaxf(s, 1.f);
  }
}

// softmax over one row of the fp32 score chunk (chunk = 16 z-slices)
__global__ __launch_bounds__(256) void softmax_k(float* sc, const float* maskf, int zbase) {
  int row = blockIdx.x;                 // [0, 16*1024)
  int gz = zbase + (row >> 10);
  int b = gz >> 4;
  const long long base = (long long)row * kS;
  int tid = threadIdx.x;
  float s[4];
#pragma unroll
  for (int i = 0; i < 4; i++) {
    int j = tid + i * 256;
    float v = sc[base + j] * kScale;
    if (maskf[b * kS + j] != 0.f) v = -1e30f;
    s[i] = v;
  }
  float mx = blockReduceMax(fmaxf(fmaxf(s[0], s[1]), fmaxf(s[2], s[3])));
  float sum = 0;
#pragma unroll
  for (int i = 0; i < 4; i++) { s[i] = __expf(s[i] - mx); sum += s[i]; }
  sum = blockReduceSum(sum);
  float inv = 1.f / sum;
#pragma unroll
  for (int i = 0; i < 4; i++) {
    int j = tid + i * 256;
    sc[base + j] = s[i] * inv;
  }
}

__global__ __launch_bounds__(256) void ln_k(const float* basef, const void* baseb,
                                            const int* dflag, int baseIsIn,
                                            const float* add1, const float* add2,
                                            const void* g, const void* bb,
                                            float* outf, void* outFinal) {
  const int f32in = dflag[0];
  const int baseF32 = baseIsIn && f32in;
  long long base = (long long)blockIdx.x * kD;
  int tid = threadIdx.x;
  float v[4]; float s = 0;
#pragma unroll
  for (int i = 0; i < 4; i++) {
    int d = tid + i * 256;
    float x = basef ? basef[base + d] : ldIn(baseb, base + d, baseF32);
    if (add1) x += add1[base + d];
    if (add2) x += add2[base + d];
    v[i] = x; s += x;
  }
  float mean = blockReduceSum(s) * (1.f / kD);
  float q = 0;
#pragma unroll
  for (int i = 0; i < 4; i++) { float d0 = v[i] - mean; q += d0 * d0; }
  float var = blockReduceSum(q) * (1.f / kD);
  float rstd = rsqrtf(var + 1e-5f);
#pragma unroll
  for (int i = 0; i < 4; i++) {
    int d = tid + i * 256;
    float y = (v[i] - mean) * rstd * ldIn(g, d, f32in) + ldIn(bb, d, f32in);
    if (outf) outf[base + d] = y;
    if (outFinal) stOut(outFinal, base + d, y, f32in);
  }
}

__global__ __launch_bounds__(256) void router_k(const float* xf, const void* gw, void* outBase,
                                                int* sel, float* wsel, int* counts,
                                                const int* dflag) {
  const int f32in = dflag[0];
  int wv = threadIdx.x >> 6, lane = threadIdx.x & 63;
  int t = blockIdx.x * 4 + wv;
  const float* xr = xf + (long long)t * kD;
  float acc[8];
#pragma unroll
  for (int e = 0; e < 8; e++) acc[e] = 0.f;
  for (int d = lane; d < kD; d += 64) {
    float xv = xr[d];
    float gv[8];
    ld8f(gw, (long long)d * 8, f32in, gv);
#pragma unroll
    for (int e = 0; e < 8; e++) acc[e] += xv * gv[e];
  }
#pragma unroll
  for (int o = 32; o; o >>= 1) {
#pragma unroll
    for (int e = 0; e < 8; e++) acc[e] += __shfl_down(acc[e], o, 64);
  }
  if (lane == 0) {
    float mx = acc[0];
    for (int e = 1; e < 8; e++) mx = fmaxf(mx, acc[e]);
    float p[8], sum = 0;
    for (int e = 0; e < 8; e++) { p[e] = expf(acc[e] - mx); sum += p[e]; }
    float inv = 1.f / sum;
    for (int e = 0; e < 8; e++) {
      p[e] *= inv;
      stOut(outBase, kOutProbs + (long long)t * 8 + e, p[e], f32in);
    }
    int e0 = 0; for (int e = 1; e < 8; e++) if (p[e] > p[e0]) e0 = e;
    int e1 = -1; for (int e = 0; e < 8; e++) { if (e == e0) continue; if (e1 < 0 || p[e] > p[e1]) e1 = e; }
    float s2 = p[e0] + p[e1];
    sel[t * 2] = e0; sel[t * 2 + 1] = e1;
    wsel[t * 2] = p[e0] / s2; wsel[t * 2 + 1] = p[e1] / s2;
    atomicAdd(&counts[e0], 1); atomicAdd(&counts[e1], 1);
  }
}

__global__ void offsets_k(const int* counts, int* offsets) {
  if (threadIdx.x == 0) {
    int s = 0;
    for (int e = 0; e < kE; e++) { offsets[e] = s; s += counts[e]; }
    offsets[kE] = s;
  }
}

__global__ void place_k(const int* sel, const float* wsel, const int* offsets, int* fill,
                        int* aidxArr, int* slotArr, float* wgtArr) {
  int t = blockIdx.x * 256 + threadIdx.x;
  if (t >= kTok) return;
  for (int s = 0; s < 2; s++) {
    int e = sel[t * 2 + s];
    int pos = offsets[e] + atomicAdd(&fill[e], 1);
    aidxArr[pos] = t; slotArr[pos] = s; wgtArr[pos] = wsel[t * 2 + s];
  }
}

__global__ void meanacc_k(const int* counts, const int* offsets, const int* aidxArr,
                          const int* slotArr, const float* keepf, const float* contrib,
                          float* meanAcc) {
  int e = blockIdx.x, dc = blockIdx.y, ch = blockIdx.z;
  int d = dc * 128 + threadIdx.x;
  int cnt = counts[e], off = offsets[e];
  int per = (cnt + 15) / 16;
  int i0 = ch * per, i1 = i0 + per; if (i1 > cnt) i1 = cnt;
  float a0 = 0, a1 = 0;
  for (int i = i0; i < i1; i++) {
    int a = off + i; int t = aidxArr[a];
    if (keepf[t] != 0.f) {
      float v = contrib[((long long)slotArr[a] * kTok + t) * kD + d];
      if (t < kS) a0 += v; else a1 += v;
    }
  }
  if (a0 != 0.f) atomicAdd(&meanAcc[(e * 2 + 0) * kD + d], a0);
  if (a1 != 0.f) atomicAdd(&meanAcc[(e * 2 + 1) * kD + d], a1);
}

__global__ __launch_bounds__(256) void dots_k(const float* meanAcc, const void* cls_w,
                                              const float* denom, float* dots,
                                              const int* dflag) {
  const int f32in = dflag[0];
  int eb = blockIdx.x;
  int b = eb & 1;
  float s = 0;
  for (int d = threadIdx.x; d < kD; d += 256)
    s += meanAcc[(long long)eb * kD + d] * ldIn(cls_w, d, f32in);
  s = blockReduceSum(s);
  if (threadIdx.x == 0) dots[eb] = s / denom[b];
}

__global__ void final_logits_k(const float* dots, const void* cls_b, void* outBase,
                               const int* dflag) {
  const int f32in = dflag[0];
  int i = threadIdx.x;
  if (i < kE * kB) {
    int e = i >> 1, b = i & 1;
    float s = ldIn(cls_b, 0, f32in);
    for (int e2 = 0; e2 <= e; e2++) s += dots[e2 * 2 + b];
    stOut(outBase, kOutLogits + e * kB + b, s, f32in);
  }
}

// ------------------------------------------------------------------ host ----
extern "C" void kernel_launch(void* const* d_in, const int* in_sizes, int n_in,
                              void* d_out, int out_size, void* d_ws, size_t ws_size,
                              hipStream_t stream) {
  (void)in_sizes; (void)n_in; (void)out_size; (void)ws_size;

  const void* x_in  = d_in[0];
  const void* enc   = d_in[1];
  const void* srcm = d_in[2];
  const void* tgtm = d_in[3];
  const void* midm = d_in[4];
  const void* ln1g = d_in[5];  const void* ln1b = d_in[6];
  const void* ln2g = d_in[7];  const void* ln2b = d_in[8];
  const void* ln3g = d_in[9];  const void* ln3b = d_in[10];
  const void* sa_wq = d_in[11]; const void* sa_wk = d_in[12];
  const void* sa_wv = d_in[13]; const void* sa_wo = d_in[14];
  const void* sa_bo = d_in[15];
  const void* ca_wq = d_in[16]; const void* ca_wk = d_in[17];
  const void* ca_wv = d_in[18]; const void* ca_wo = d_in[19];
  const void* ca_bo = d_in[20];
  const void* gate_w = d_in[21];
  const void* cls_w  = d_in[22]; const void* cls_b = d_in[23];
  const void* moe_w1 = d_in[24];
  const void* moe_w2 = d_in[25];
  const void* moe_w3 = d_in[26];

  char* wp = (char*)d_ws;
  size_t off = 0;
  auto alloc = [&](size_t bytes) -> void* {
    void* p = wp + off; off = (off + bytes + 255) & ~(size_t)255; return p;
  };
  // 16-z-slice fp32 score chunk; MoE Hbuf/contrib alias into it (disjoint phases)
  float* scFP = (float*)alloc((size_t)16 * kS * kS * 4);          // 67.1 MB
  u16*   Hbuf = (u16*)scFP;                                        // 16.8 MB
  float* contrib = (float*)((char*)scFP + (size_t)2 * kTok * kHID * 2); // 16.8 MB
  float* qf    = (float*)alloc((size_t)kTok * kD * 4);
  float* kf    = (float*)alloc((size_t)kTok * kD * 4);
  float* vf    = (float*)alloc((size_t)kTok * kD * 4);
  float* attnof= (float*)alloc((size_t)kTok * kD * 4);
  float* obuf  = (float*)alloc((size_t)kTok * kD * 4);
  float* x1f   = (float*)alloc((size_t)kTok * kD * 4);
  float* x2f   = (float*)alloc((size_t)kTok * kD * 4);
  float* meanAcc = (float*)alloc((size_t)kE * kB * kD * 4);
  float* srcf = (float*)alloc(kTok * 4);
  float* padf = (float*)alloc(kTok * 4);
  float* keepf = (float*)alloc(kTok * 4);
  float* denom = (float*)alloc(2 * 4);
  int* counts = (int*)alloc(256); int* fill = counts + 8;
  int* offsets = (int*)alloc(256);
  int* sel = (int*)alloc(kTok * 2 * 4);
  float* wsel = (float*)alloc(kTok * 2 * 4);
  int* aidxArr = (int*)alloc(2 * kTok * 4);
  int* slotArr = (int*)alloc(2 * kTok * 4);
  float* wgtArr = (float*)alloc(2 * kTok * 4);
  float* dots = (float*)alloc(256);
  int* dflag = (int*)alloc(256);

  auto g3 = [&](const void* A, const void* Bmat, float* C, int M, int N, int K,
                int lda, int ldb, int ldc, int bT, int aF, int bF,
                long long a0, long long a1, long long b0, long long b1,
                long long c0, long long c1, int zdiv, int zA, int zB, int zC,
                int nz, const void* bias) {
    G3P p;
    p.A = A; p.Bm = Bmat; p.C = C;
    p.a0 = a0; p.a1 = a1; p.b0 = b0; p.b1 = b1; p.c0 = c0; p.c1 = c1;
    p.zdiv = zdiv; p.zA = zA; p.zB = zB; p.zC = zC;
    p.lda = lda; p.ldb = ldb; p.ldc = ldc; p.M = M; p.N = N; p.K = K;
    p.bT = bT; p.aF = aF; p.bF = bF; p.dflag = dflag; p.bias = bias;
    dim3 grid(N / 64, M / 64, nz);
    gemm3_k<<<grid, dim3(256), 0, stream>>>(p);
  };

  hipMemsetAsync(counts, 0, 64, stream);
  hipMemsetAsync(meanAcc, 0, (size_t)kE * kB * kD * 4, stream);
  detect_k<<<1, 256, 0, stream>>>(x_in, dflag);
  maskprep_k<<<1, 256, 0, stream>>>(srcm, tgtm, midm, srcf, padf, keepf, denom);

  const long long SD = (long long)kS * kD;
  const long long SS = (long long)kS * kS;

  auto attention = [&](const void* qsrc, int qF, const void* ksrc, int kvF,
                       const void* wq, const void* wk, const void* wv,
                       const void* wo, const void* bo, const float* maskf) {
    g3(qsrc, wq, qf, kTok, kD, kD, kD, kD, kD, 0, qF, 1, 0,0,0,0,0,0, 1,0,0,0, 1, nullptr);
    g3(ksrc, wk, kf, kTok, kD, kD, kD, kD, kD, 0, kvF, 1, 0,0,0,0,0,0, 1,0,0,0, 1, nullptr);
    g3(ksrc, wv, vf, kTok, kD, kD, kD, kD, kD, 0, kvF, 1, 0,0,0,0,0,0, 1,0,0,0, 1, nullptr);
    for (int c = 0; c < 2; c++) {
      int zb = c * 16;
      // scores: [16,1024,1024] fp32 chunk
      g3(qf, kf, scFP, kS, kS, kDH, kD, kD, kS, 1, 2, 2,
         SD, 64, SD, 64, 0, SS, 16, zb, zb, 0, 16, nullptr);
      softmax_k<<<16 * kS, 256, 0, stream>>>(scFP, maskf, zb);
      // PV
      g3(scFP, vf, attnof, kS, kDH, kS, kS, kD, kD, 0, 2, 2,
         0, SS, SD, 64, SD, 64, 16, 0, zb, zb, 16, nullptr);
    }
    g3(attnof, wo, obuf, kTok, kD, kD, kD, kD, kD, 0, 2, 1, 0,0,0,0,0,0, 1,0,0,0, 1, bo);
  };

  // ---- self attention ----
  attention(x_in, 1, x_in, 1, sa_wq, sa_wk, sa_wv, sa_wo, sa_bo, padf);
  ln_k<<<kTok, 256, 0, stream>>>(nullptr, x_in, dflag, 1, obuf, nullptr, ln1g, ln1b, x1f, nullptr);

  // ---- cross attention ----
  attention(x1f, 2, enc, 1, ca_wq, ca_wk, ca_wv, ca_wo, ca_bo, srcf);
  ln_k<<<kTok, 256, 0, stream>>>(x1f, nullptr, dflag, 0, obuf, nullptr, ln2g, ln2b, x2f, nullptr);

  // ---- MoE ----
  router_k<<<kTok / 4, 256, 0, stream>>>(x2f, gate_w, d_out, sel, wsel, counts, dflag);
  offsets_k<<<1, 64, 0, stream>>>(counts, offsets);
  place_k<<<kTok / 256, 256, 0, stream>>>(sel, wsel, offsets, fill, aidxArr, slotArr, wgtArr);
  moe13_k<<<dim3(kHID / 64, kTok / 64, kE), 256, 0, stream>>>(x2f, moe_w1, moe_w3, counts, offsets, aidxArr, Hbuf, dflag);
  w2_k<<<dim3(kD / 64, kTok / 64, kE), 256, 0, stream>>>(Hbuf, moe_w2, counts, offsets, aidxArr, slotArr, wgtArr, contrib, dflag);
  meanacc_k<<<dim3(kE, kD / 128, 16), 128, 0, stream>>>(counts, offsets, aidxArr, slotArr, keepf, contrib, meanAcc);
  dots_k<<<kE * kB, 256, 0, stream>>>(meanAcc, cls_w, denom, dots, dflag);
  final_logits_k<<<1, 64, 0, stream>>>(dots, cls_b, d_out, dflag);
  ln_k<<<kTok, 256, 0, stream>>>(x2f, nullptr, dflag, 0, contrib, contrib + (size_t)kTok * kD, ln3g, ln3b, nullptr, d_out);
}

// Round 4
// 1332.130 us; speedup vs baseline: 1.1411x; 1.1411x over previous
//
#include <hip/hip_runtime.h>
#include <hip/hip_bf16.h>
#include <math.h>

constexpr int kB   = 2;
constexpr int kS   = 1024;
constexpr int kD   = 1024;
constexpr int kH   = 16;
constexpr int kDH  = 64;
constexpr int kHID = 2048;
constexpr int kE   = 8;
constexpr int kTok = kB * kS;         // 2048
constexpr float kScale = 0.125f;
constexpr long long kOutLogits = (long long)kTok * kD;
constexpr long long kOutProbs  = kOutLogits + kE * kB;

using u16 = unsigned short;
typedef __attribute__((ext_vector_type(8))) short short8;
typedef __attribute__((ext_vector_type(4))) float f32x4;

__device__ __forceinline__ float b2f(u16 u) {
  union { unsigned int i; float f; } c; c.i = ((unsigned int)u) << 16; return c.f;
}
__device__ __forceinline__ u16 f2b(float f) {
  __hip_bfloat16 h = __float2bfloat16(f);
  u16 u; __builtin_memcpy(&u, &h, 2); return u;
}
__device__ __forceinline__ float ldIn(const void* p, long long i, int f32) {
  return f32 ? ((const float*)p)[i] : b2f(((const u16*)p)[i]);
}
__device__ __forceinline__ void ld8f(const void* p, long long i, int f32, float v[8]) {
  if (f32) {
    const float* fp = (const float*)p + i;
    float4 a = *(const float4*)fp, b = *(const float4*)(fp + 4);
    v[0]=a.x; v[1]=a.y; v[2]=a.z; v[3]=a.w; v[4]=b.x; v[5]=b.y; v[6]=b.z; v[7]=b.w;
  } else {
    short8 s = *(const short8*)((const u16*)p + i);
#pragma unroll
    for (int j = 0; j < 8; j++) v[j] = b2f((u16)s[j]);
  }
}
__device__ __forceinline__ void stOut(void* base, long long i, float v, int f32) {
  if (f32) ((float*)base)[i] = v; else ((u16*)base)[i] = f2b(v);
}

__device__ __forceinline__ float blockReduceSum(float v) {
  __shared__ float sh[4];
  int lane = threadIdx.x & 63, wv = threadIdx.x >> 6;
#pragma unroll
  for (int o = 32; o; o >>= 1) v += __shfl_down(v, o, 64);
  __syncthreads();
  if (lane == 0) sh[wv] = v;
  __syncthreads();
  return sh[0] + sh[1] + sh[2] + sh[3];
}
__device__ __forceinline__ float blockReduceMax(float v) {
  __shared__ float sh[4];
  int lane = threadIdx.x & 63, wv = threadIdx.x >> 6;
#pragma unroll
  for (int o = 32; o; o >>= 1) v = fmaxf(v, __shfl_down(v, o, 64));
  __syncthreads();
  if (lane == 0) sh[wv] = v;
  __syncthreads();
  return fmaxf(fmaxf(sh[0], sh[1]), fmaxf(sh[2], sh[3]));
}

// ------------------------------------------------------------- detect -------
__global__ void detect_k(const void* x, int* dflag) {
  __shared__ int sg, st;
  int tid = threadIdx.x;
  if (tid == 0) { sg = 0; st = 0; }
  __syncthreads();
  const unsigned int* w = (const unsigned int*)x;
  int good = 0, tot = 0;
  for (int i = tid; i < 1024; i += 256) {
    unsigned int lo = w[i] & 0xffffu;
    if (lo) {
      tot++;
      unsigned int e = (lo >> 7) & 0xffu;
      if (e >= 97 && e <= 159) good++;
    }
  }
  atomicAdd(&sg, good); atomicAdd(&st, tot);
  __syncthreads();
  if (tid == 0) dflag[0] = (sg * 10 < st * 9) ? 1 : 0;
}

// --------------------------------------- high-precision split-bf16 GEMM -----
// C[M,N] (fp32) = A[M,K] @ B; A,B split hi+lo bf16; 3 MFMA terms
// (hh + hl + lh; ll dropped, rel err ~1.5e-5).
// B staged in fragment-ordered LDS layout B2[kgroup][n][k%8] so both the
// staging write (b128, contiguous 1KB/wave) and the fragment read
// (16B/lane, 2-way alias) are bank-conflict-free.
struct G3P {
  const void* A; const void* Bm; float* C;
  long long a0, a1, b0, b1, c0, c1;
  int zdiv, zA, zB, zC;
  int lda, ldb, ldc, M, N, K;
  int bT, aF, bF;
  const int* dflag;
  const void* bias;
};

__global__ __launch_bounds__(256) void gemm3_k(G3P p) {
  const int z = blockIdx.z;
  const int m0 = blockIdx.y * 64, n0 = blockIdx.x * 64;
  const int f32in = p.dflag[0];
  const int af32 = (p.aF == 2) || (p.aF == 1 && f32in);
  const int bf32 = (p.bF == 2) || (p.bF == 1 && f32in);
  const int gA = z + p.zA, gB = z + p.zB, gC = z + p.zC;
  const long long aoff = (long long)(gA / p.zdiv) * p.a0 + (long long)(gA % p.zdiv) * p.a1;
  const long long boff = (long long)(gB / p.zdiv) * p.b0 + (long long)(gB % p.zdiv) * p.b1;
  const long long coff = (long long)(gC / p.zdiv) * p.c0 + (long long)(gC % p.zdiv) * p.c1;

  __shared__ short Ah[64][32], Al[64][32];
  __shared__ short Bh2[4][64][8], Bl2[4][64][8];

  const int tid = threadIdx.x;
  const int wave = tid >> 6, lane = tid & 63;
  const int wr = wave >> 1, wc = wave & 1;
  const int quad = lane >> 4, l16 = lane & 15;

  const int arow = tid >> 2, ak = (tid & 3) * 8;
  const long long abase = aoff + (long long)(m0 + arow) * p.lda + ak;
  const int btn = tid >> 2, btkg = tid & 3;   // bT=1 coords
  const int bn = tid & 63, bkg = tid >> 6;    // bT=0 coords

  f32x4 acc[2][2];
  const f32x4 z4 = {0.f, 0.f, 0.f, 0.f};
  acc[0][0] = z4; acc[0][1] = z4; acc[1][0] = z4; acc[1][1] = z4;

  for (int k0 = 0; k0 < p.K; k0 += 32) {
    float va[8];
    ld8f(p.A, abase + k0, af32, va);
    short8 ah8, al8;
#pragma unroll
    for (int j = 0; j < 8; j++) {
      u16 h = f2b(va[j]);
      ah8[j] = (short)h;
      al8[j] = (short)f2b(va[j] - b2f(h));
    }
    *(short8*)(&Ah[arow][ak]) = ah8;
    *(short8*)(&Al[arow][ak]) = al8;

    short8 bh8, bl8;
    if (p.bT) {
      float vb[8];
      ld8f(p.Bm, boff + (long long)(n0 + btn) * p.ldb + k0 + btkg * 8, bf32, vb);
#pragma unroll
      for (int j = 0; j < 8; j++) {
        u16 h = f2b(vb[j]);
        bh8[j] = (short)h;
        bl8[j] = (short)f2b(vb[j] - b2f(h));
      }
      *(short8*)(&Bh2[btkg][btn][0]) = bh8;
      *(short8*)(&Bl2[btkg][btn][0]) = bl8;
    } else {
#pragma unroll
      for (int j = 0; j < 8; j++) {
        float v = ldIn(p.Bm, boff + (long long)(k0 + bkg * 8 + j) * p.ldb + n0 + bn, bf32);
        u16 h = f2b(v);
        bh8[j] = (short)h;
        bl8[j] = (short)f2b(v - b2f(h));
      }
      *(short8*)(&Bh2[bkg][bn][0]) = bh8;
      *(short8*)(&Bl2[bkg][bn][0]) = bl8;
    }
    __syncthreads();
    short8 ah0 = *(const short8*)(&Ah[wr * 32 + l16][quad * 8]);
    short8 ah1 = *(const short8*)(&Ah[wr * 32 + 16 + l16][quad * 8]);
    short8 al0 = *(const short8*)(&Al[wr * 32 + l16][quad * 8]);
    short8 al1 = *(const short8*)(&Al[wr * 32 + 16 + l16][quad * 8]);
    short8 bh0 = *(const short8*)(&Bh2[quad][wc * 32 + l16][0]);
    short8 bh1 = *(const short8*)(&Bh2[quad][wc * 32 + 16 + l16][0]);
    short8 bl0 = *(const short8*)(&Bl2[quad][wc * 32 + l16][0]);
    short8 bl1 = *(const short8*)(&Bl2[quad][wc * 32 + 16 + l16][0]);
    acc[0][0] = __builtin_amdgcn_mfma_f32_16x16x32_bf16(al0, bh0, acc[0][0], 0, 0, 0);
    acc[0][1] = __builtin_amdgcn_mfma_f32_16x16x32_bf16(al0, bh1, acc[0][1], 0, 0, 0);
    acc[1][0] = __builtin_amdgcn_mfma_f32_16x16x32_bf16(al1, bh0, acc[1][0], 0, 0, 0);
    acc[1][1] = __builtin_amdgcn_mfma_f32_16x16x32_bf16(al1, bh1, acc[1][1], 0, 0, 0);
    acc[0][0] = __builtin_amdgcn_mfma_f32_16x16x32_bf16(ah0, bl0, acc[0][0], 0, 0, 0);
    acc[0][1] = __builtin_amdgcn_mfma_f32_16x16x32_bf16(ah0, bl1, acc[0][1], 0, 0, 0);
    acc[1][0] = __builtin_amdgcn_mfma_f32_16x16x32_bf16(ah1, bl0, acc[1][0], 0, 0, 0);
    acc[1][1] = __builtin_amdgcn_mfma_f32_16x16x32_bf16(ah1, bl1, acc[1][1], 0, 0, 0);
    acc[0][0] = __builtin_amdgcn_mfma_f32_16x16x32_bf16(ah0, bh0, acc[0][0], 0, 0, 0);
    acc[0][1] = __builtin_amdgcn_mfma_f32_16x16x32_bf16(ah0, bh1, acc[0][1], 0, 0, 0);
    acc[1][0] = __builtin_amdgcn_mfma_f32_16x16x32_bf16(ah1, bh0, acc[1][0], 0, 0, 0);
    acc[1][1] = __builtin_amdgcn_mfma_f32_16x16x32_bf16(ah1, bh1, acc[1][1], 0, 0, 0);
    __syncthreads();
  }

#pragma unroll
  for (int sm = 0; sm < 2; sm++) {
#pragma unroll
    for (int r = 0; r < 4; r++) {
      int row = m0 + wr * 32 + sm * 16 + quad * 4 + r;
#pragma unroll
      for (int sn = 0; sn < 2; sn++) {
        int col = n0 + wc * 32 + sn * 16 + l16;
        float v = acc[sm][sn][r];
        if (p.bias) v += ldIn(p.bias, col, f32in);
        p.C[coff + (long long)row * p.ldc + col] = v;
      }
    }
  }
}

// -------------------------------------------- fused MoE W1/W3 + SwiGLU ------
__global__ __launch_bounds__(256) void moe13_k(const float* Xf, const void* W1, const void* W3,
                                               const int* counts, const int* offsets,
                                               const int* aidxArr, u16* Hbuf, const int* dflag) {
  int e = blockIdx.z;
  int Meff = counts[e];
  int m0 = blockIdx.y * 64;
  if (m0 >= Meff) return;
  int n0 = blockIdx.x * 64;
  int csr = offsets[e];
  const int wf32 = dflag[0];
  const long long ebase = (long long)e * kD * kHID;
  __shared__ short As[64][32];
  __shared__ short B1s2[4][64][8], B3s2[4][64][8];
  int tid = threadIdx.x, wave = tid >> 6, lane = tid & 63;
  int wr = wave >> 1, wc = wave & 1, quad = lane >> 4, l16 = lane & 15;
  int arow = tid >> 2, ak = (tid & 3) * 8;
  int grow = m0 + arow; if (grow >= Meff) grow = Meff - 1;
  const float* Aptr = Xf + (long long)aidxArr[csr + grow] * kD + ak;
  const int bn = tid & 63, bkg = tid >> 6;
  f32x4 acc1[2][2], acc3[2][2];
  const f32x4 z4 = {0.f, 0.f, 0.f, 0.f};
  acc1[0][0] = z4; acc1[0][1] = z4; acc1[1][0] = z4; acc1[1][1] = z4;
  acc3[0][0] = z4; acc3[0][1] = z4; acc3[1][0] = z4; acc3[1][1] = z4;

  for (int k0 = 0; k0 < kD; k0 += 32) {
    float4 a0v = *(const float4*)(Aptr + k0);
    float4 a1v = *(const float4*)(Aptr + k0 + 4);
    short8 a8;
    a8[0] = (short)f2b(a0v.x); a8[1] = (short)f2b(a0v.y);
    a8[2] = (short)f2b(a0v.z); a8[3] = (short)f2b(a0v.w);
    a8[4] = (short)f2b(a1v.x); a8[5] = (short)f2b(a1v.y);
    a8[6] = (short)f2b(a1v.z); a8[7] = (short)f2b(a1v.w);
    *(short8*)(&As[arow][ak]) = a8;
    short8 b1, b3;
#pragma unroll
    for (int j = 0; j < 8; j++) {
      long long bidx = ebase + (long long)(k0 + bkg * 8 + j) * kHID + n0 + bn;
      b1[j] = (short)f2b(ldIn(W1, bidx, wf32));
      b3[j] = (short)f2b(ldIn(W3, bidx, wf32));
    }
    *(short8*)(&B1s2[bkg][bn][0]) = b1;
    *(short8*)(&B3s2[bkg][bn][0]) = b3;
    __syncthreads();
    short8 af0 = *(const short8*)(&As[wr * 32 + l16][quad * 8]);
    short8 af1 = *(const short8*)(&As[wr * 32 + 16 + l16][quad * 8]);
    short8 c10 = *(const short8*)(&B1s2[quad][wc * 32 + l16][0]);
    short8 c11 = *(const short8*)(&B1s2[quad][wc * 32 + 16 + l16][0]);
    short8 c30 = *(const short8*)(&B3s2[quad][wc * 32 + l16][0]);
    short8 c31 = *(const short8*)(&B3s2[quad][wc * 32 + 16 + l16][0]);
    acc1[0][0] = __builtin_amdgcn_mfma_f32_16x16x32_bf16(af0, c10, acc1[0][0], 0, 0, 0);
    acc1[0][1] = __builtin_amdgcn_mfma_f32_16x16x32_bf16(af0, c11, acc1[0][1], 0, 0, 0);
    acc1[1][0] = __builtin_amdgcn_mfma_f32_16x16x32_bf16(af1, c10, acc1[1][0], 0, 0, 0);
    acc1[1][1] = __builtin_amdgcn_mfma_f32_16x16x32_bf16(af1, c11, acc1[1][1], 0, 0, 0);
    acc3[0][0] = __builtin_amdgcn_mfma_f32_16x16x32_bf16(af0, c30, acc3[0][0], 0, 0, 0);
    acc3[0][1] = __builtin_amdgcn_mfma_f32_16x16x32_bf16(af0, c31, acc3[0][1], 0, 0, 0);
    acc3[1][0] = __builtin_amdgcn_mfma_f32_16x16x32_bf16(af1, c30, acc3[1][0], 0, 0, 0);
    acc3[1][1] = __builtin_amdgcn_mfma_f32_16x16x32_bf16(af1, c31, acc3[1][1], 0, 0, 0);
    __syncthreads();
  }
#pragma unroll
  for (int sm = 0; sm < 2; sm++) {
#pragma unroll
    for (int r = 0; r < 4; r++) {
      int row = m0 + wr * 32 + sm * 16 + quad * 4 + r;
      if (row >= Meff) continue;
#pragma unroll
      for (int sn = 0; sn < 2; sn++) {
        int col = n0 + wc * 32 + sn * 16 + l16;
        float g1 = acc1[sm][sn][r], g3 = acc3[sm][sn][r];
        float h = (g1 / (1.f + __expf(-g1))) * g3;
        Hbuf[(long long)(csr + row) * kHID + col] = f2b(h);
      }
    }
  }
}

// ------------------------------------------------ MoE W2 + scatter ---------
__global__ __launch_bounds__(256) void w2_k(const u16* Hbuf, const void* W2,
                                            const int* counts, const int* offsets,
                                            const int* aidxArr, const int* slotArr,
                                            const float* wgtArr, float* contrib,
                                            const int* dflag) {
  int e = blockIdx.z;
  int Meff = counts[e];
  int m0 = blockIdx.y * 64;
  if (m0 >= Meff) return;
  int n0 = blockIdx.x * 64;
  int csr = offsets[e];
  const int wf32 = dflag[0];
  const long long ebase = (long long)e * kHID * kD;
  __shared__ short As[64][32];
  __shared__ short Bs2[4][64][8];
  int tid = threadIdx.x, wave = tid >> 6, lane = tid & 63;
  int wr = wave >> 1, wc = wave & 1, quad = lane >> 4, l16 = lane & 15;
  int arow = tid >> 2, ak = (tid & 3) * 8;
  int grow = m0 + arow; if (grow >= Meff) grow = Meff - 1;
  const u16* Aptr = Hbuf + (long long)(csr + grow) * kHID + ak;
  const int bn = tid & 63, bkg = tid >> 6;
  f32x4 acc[2][2];
  const f32x4 z4 = {0.f, 0.f, 0.f, 0.f};
  acc[0][0] = z4; acc[0][1] = z4; acc[1][0] = z4; acc[1][1] = z4;

  for (int k0 = 0; k0 < kHID; k0 += 32) {
    *(short8*)(&As[arow][ak]) = *(const short8*)(Aptr + k0);
    short8 b8;
#pragma unroll
    for (int j = 0; j < 8; j++)
      b8[j] = (short)f2b(ldIn(W2, ebase + (long long)(k0 + bkg * 8 + j) * kD + n0 + bn, wf32));
    *(short8*)(&Bs2[bkg][bn][0]) = b8;
    __syncthreads();
    short8 af0 = *(const short8*)(&As[wr * 32 + l16][quad * 8]);
    short8 af1 = *(const short8*)(&As[wr * 32 + 16 + l16][quad * 8]);
    short8 bf0 = *(const short8*)(&Bs2[quad][wc * 32 + l16][0]);
    short8 bf1 = *(const short8*)(&Bs2[quad][wc * 32 + 16 + l16][0]);
    acc[0][0] = __builtin_amdgcn_mfma_f32_16x16x32_bf16(af0, bf0, acc[0][0], 0, 0, 0);
    acc[0][1] = __builtin_amdgcn_mfma_f32_16x16x32_bf16(af0, bf1, acc[0][1], 0, 0, 0);
    acc[1][0] = __builtin_amdgcn_mfma_f32_16x16x32_bf16(af1, bf0, acc[1][0], 0, 0, 0);
    acc[1][1] = __builtin_amdgcn_mfma_f32_16x16x32_bf16(af1, bf1, acc[1][1], 0, 0, 0);
    __syncthreads();
  }
#pragma unroll
  for (int sm = 0; sm < 2; sm++) {
#pragma unroll
    for (int r = 0; r < 4; r++) {
      int row = m0 + wr * 32 + sm * 16 + quad * 4 + r;
      if (row >= Meff) continue;
      int a = csr + row;
      int t = aidxArr[a]; int s = slotArr[a]; float w = wgtArr[a];
#pragma unroll
      for (int sn = 0; sn < 2; sn++) {
        int col = n0 + wc * 32 + sn * 16 + l16;
        contrib[((long long)s * kTok + t) * kD + col] = acc[sm][sn][r] * w;
      }
    }
  }
}

// ------------------------------------------------------------ small ops -----
__global__ void maskprep_k(const void* srcm, const void* tgtm, const void* midm,
                           float* srcf, float* padf, float* keepf, float* denom) {
  __shared__ int okInt, okFloat, okBf16;
  int tid = threadIdx.x;
  if (tid == 0) { okInt = 1; okFloat = 1; okBf16 = 1; }
  __syncthreads();
  const unsigned int* wi = (const unsigned int*)tgtm;
  const float* wf = (const float*)tgtm;
  int badI = 0, badF = 0, badB = 0;
  for (int i = tid; i < 512; i += 256) {
    unsigned int w = wi[i];
    if (w > 1u) badI = 1;
    float f = wf[i];
    if (!(f == 0.f || f == 1.f)) badF = 1;
    unsigned int lo = w & 0xffffu, hi = w >> 16;
    if (!((lo == 0 || lo == 0x3f80u) && (hi == 0 || hi == 0x3f80u))) badB = 1;
  }
  if (badI) atomicExch(&okInt, 0);
  if (badF) atomicExch(&okFloat, 0);
  if (badB) atomicExch(&okBf16, 0);
  __syncthreads();
  int mode = okInt ? 0 : (okFloat ? 2 : (okBf16 ? 3 : 1));
  for (int i = tid; i < kTok; i += 256) {
    bool sv, pv, mv;
    if (mode == 0) {
      sv = ((const int*)srcm)[i] != 0; pv = ((const int*)tgtm)[i] != 0; mv = ((const int*)midm)[i] != 0;
    } else if (mode == 2) {
      sv = ((const float*)srcm)[i] != 0.f; pv = ((const float*)tgtm)[i] != 0.f; mv = ((const float*)midm)[i] != 0.f;
    } else if (mode == 3) {
      sv = ((const u16*)srcm)[i] != 0; pv = ((const u16*)tgtm)[i] != 0; mv = ((const u16*)midm)[i] != 0;
    } else {
      sv = ((const unsigned char*)srcm)[i] != 0; pv = ((const unsigned char*)tgtm)[i] != 0; mv = ((const unsigned char*)midm)[i] != 0;
    }
    srcf[i] = sv ? 1.f : 0.f;
    padf[i] = pv ? 1.f : 0.f;
    keepf[i] = (pv || mv) ? 0.f : 1.f;
  }
  __syncthreads();
  if (tid < 2) {
    float s = 0;
    for (int j = 0; j < kS; j++) s += keepf[tid * kS + j];
    denom[tid] = fmaxf(s, 1.f);
  }
}

__global__ __launch_bounds__(256) void softmax_k(float* sc, const float* maskf, int zbase) {
  int row = blockIdx.x;
  int gz = zbase + (row >> 10);
  int b = gz >> 4;
  const long long base = (long long)row * kS;
  int tid = threadIdx.x;
  float s[4];
#pragma unroll
  for (int i = 0; i < 4; i++) {
    int j = tid + i * 256;
    float v = sc[base + j] * kScale;
    if (maskf[b * kS + j] != 0.f) v = -1e30f;
    s[i] = v;
  }
  float mx = blockReduceMax(fmaxf(fmaxf(s[0], s[1]), fmaxf(s[2], s[3])));
  float sum = 0;
#pragma unroll
  for (int i = 0; i < 4; i++) { s[i] = __expf(s[i] - mx); sum += s[i]; }
  sum = blockReduceSum(sum);
  float inv = 1.f / sum;
#pragma unroll
  for (int i = 0; i < 4; i++) {
    int j = tid + i * 256;
    sc[base + j] = s[i] * inv;
  }
}

__global__ __launch_bounds__(256) void ln_k(const float* basef, const void* baseb,
                                            const int* dflag, int baseIsIn,
                                            const float* add1, const float* add2,
                                            const void* g, const void* bb,
                                            float* outf, void* outFinal) {
  const int f32in = dflag[0];
  const int baseF32 = baseIsIn && f32in;
  long long base = (long long)blockIdx.x * kD;
  int tid = threadIdx.x;
  float v[4]; float s = 0;
#pragma unroll
  for (int i = 0; i < 4; i++) {
    int d = tid + i * 256;
    float x = basef ? basef[base + d] : ldIn(baseb, base + d, baseF32);
    if (add1) x += add1[base + d];
    if (add2) x += add2[base + d];
    v[i] = x; s += x;
  }
  float mean = blockReduceSum(s) * (1.f / kD);
  float q = 0;
#pragma unroll
  for (int i = 0; i < 4; i++) { float d0 = v[i] - mean; q += d0 * d0; }
  float var = blockReduceSum(q) * (1.f / kD);
  float rstd = rsqrtf(var + 1e-5f);
#pragma unroll
  for (int i = 0; i < 4; i++) {
    int d = tid + i * 256;
    float y = (v[i] - mean) * rstd * ldIn(g, d, f32in) + ldIn(bb, d, f32in);
    if (outf) outf[base + d] = y;
    if (outFinal) stOut(outFinal, base + d, y, f32in);
  }
}

__global__ __launch_bounds__(256) void router_k(const float* xf, const void* gw, void* outBase,
                                                int* sel, float* wsel, int* counts,
                                                const int* dflag) {
  const int f32in = dflag[0];
  int wv = threadIdx.x >> 6, lane = threadIdx.x & 63;
  int t = blockIdx.x * 4 + wv;
  const float* xr = xf + (long long)t * kD;
  float acc[8];
#pragma unroll
  for (int e = 0; e < 8; e++) acc[e] = 0.f;
  for (int d = lane; d < kD; d += 64) {
    float xv = xr[d];
    float gv[8];
    ld8f(gw, (long long)d * 8, f32in, gv);
#pragma unroll
    for (int e = 0; e < 8; e++) acc[e] += xv * gv[e];
  }
#pragma unroll
  for (int o = 32; o; o >>= 1) {
#pragma unroll
    for (int e = 0; e < 8; e++) acc[e] += __shfl_down(acc[e], o, 64);
  }
  if (lane == 0) {
    float mx = acc[0];
    for (int e = 1; e < 8; e++) mx = fmaxf(mx, acc[e]);
    float p[8], sum = 0;
    for (int e = 0; e < 8; e++) { p[e] = expf(acc[e] - mx); sum += p[e]; }
    float inv = 1.f / sum;
    for (int e = 0; e < 8; e++) {
      p[e] *= inv;
      stOut(outBase, kOutProbs + (long long)t * 8 + e, p[e], f32in);
    }
    int e0 = 0; for (int e = 1; e < 8; e++) if (p[e] > p[e0]) e0 = e;
    int e1 = -1; for (int e = 0; e < 8; e++) { if (e == e0) continue; if (e1 < 0 || p[e] > p[e1]) e1 = e; }
    float s2 = p[e0] + p[e1];
    sel[t * 2] = e0; sel[t * 2 + 1] = e1;
    wsel[t * 2] = p[e0] / s2; wsel[t * 2 + 1] = p[e1] / s2;
    atomicAdd(&counts[e0], 1); atomicAdd(&counts[e1], 1);
  }
}

__global__ void offsets_k(const int* counts, int* offsets) {
  if (threadIdx.x == 0) {
    int s = 0;
    for (int e = 0; e < kE; e++) { offsets[e] = s; s += counts[e]; }
    offsets[kE] = s;
  }
}

__global__ void place_k(const int* sel, const float* wsel, const int* offsets, int* fill,
                        int* aidxArr, int* slotArr, float* wgtArr) {
  int t = blockIdx.x * 256 + threadIdx.x;
  if (t >= kTok) return;
  for (int s = 0; s < 2; s++) {
    int e = sel[t * 2 + s];
    int pos = offsets[e] + atomicAdd(&fill[e], 1);
    aidxArr[pos] = t; slotArr[pos] = s; wgtArr[pos] = wsel[t * 2 + s];
  }
}

__global__ void meanacc_k(const int* counts, const int* offsets, const int* aidxArr,
                          const int* slotArr, const float* keepf, const float* contrib,
                          float* meanAcc) {
  int e = blockIdx.x, dc = blockIdx.y, ch = blockIdx.z;
  int d = dc * 128 + threadIdx.x;
  int cnt = counts[e], off = offsets[e];
  int per = (cnt + 15) / 16;
  int i0 = ch * per, i1 = i0 + per; if (i1 > cnt) i1 = cnt;
  float a0 = 0, a1 = 0;
  for (int i = i0; i < i1; i++) {
    int a = off + i; int t = aidxArr[a];
    if (keepf[t] != 0.f) {
      float v = contrib[((long long)slotArr[a] * kTok + t) * kD + d];
      if (t < kS) a0 += v; else a1 += v;
    }
  }
  if (a0 != 0.f) atomicAdd(&meanAcc[(e * 2 + 0) * kD + d], a0);
  if (a1 != 0.f) atomicAdd(&meanAcc[(e * 2 + 1) * kD + d], a1);
}

__global__ __launch_bounds__(256) void dots_k(const float* meanAcc, const void* cls_w,
                                              const float* denom, float* dots,
                                              const int* dflag) {
  const int f32in = dflag[0];
  int eb = blockIdx.x;
  int b = eb & 1;
  float s = 0;
  for (int d = threadIdx.x; d < kD; d += 256)
    s += meanAcc[(long long)eb * kD + d] * ldIn(cls_w, d, f32in);
  s = blockReduceSum(s);
  if (threadIdx.x == 0) dots[eb] = s / denom[b];
}

__global__ void final_logits_k(const float* dots, const void* cls_b, void* outBase,
                               const int* dflag) {
  const int f32in = dflag[0];
  int i = threadIdx.x;
  if (i < kE * kB) {
    int e = i >> 1, b = i & 1;
    float s = ldIn(cls_b, 0, f32in);
    for (int e2 = 0; e2 <= e; e2++) s += dots[e2 * 2 + b];
    stOut(outBase, kOutLogits + e * kB + b, s, f32in);
  }
}

// ------------------------------------------------------------------ host ----
extern "C" void kernel_launch(void* const* d_in, const int* in_sizes, int n_in,
                              void* d_out, int out_size, void* d_ws, size_t ws_size,
                              hipStream_t stream) {
  (void)in_sizes; (void)n_in; (void)out_size; (void)ws_size;

  const void* x_in  = d_in[0];
  const void* enc   = d_in[1];
  const void* srcm = d_in[2];
  const void* tgtm = d_in[3];
  const void* midm = d_in[4];
  const void* ln1g = d_in[5];  const void* ln1b = d_in[6];
  const void* ln2g = d_in[7];  const void* ln2b = d_in[8];
  const void* ln3g = d_in[9];  const void* ln3b = d_in[10];
  const void* sa_wq = d_in[11]; const void* sa_wk = d_in[12];
  const void* sa_wv = d_in[13]; const void* sa_wo = d_in[14];
  const void* sa_bo = d_in[15];
  const void* ca_wq = d_in[16]; const void* ca_wk = d_in[17];
  const void* ca_wv = d_in[18]; const void* ca_wo = d_in[19];
  const void* ca_bo = d_in[20];
  const void* gate_w = d_in[21];
  const void* cls_w  = d_in[22]; const void* cls_b = d_in[23];
  const void* moe_w1 = d_in[24];
  const void* moe_w2 = d_in[25];
  const void* moe_w3 = d_in[26];

  char* wp = (char*)d_ws;
  size_t off = 0;
  auto alloc = [&](size_t bytes) -> void* {
    void* p = wp + off; off = (off + bytes + 255) & ~(size_t)255; return p;
  };
  float* scFP = (float*)alloc((size_t)16 * kS * kS * 4);          // 67.1 MB
  u16*   Hbuf = (u16*)scFP;                                        // 16.8 MB
  float* contrib = (float*)((char*)scFP + (size_t)2 * kTok * kHID * 2); // 16.8 MB
  float* qf    = (float*)alloc((size_t)kTok * kD * 4);
  float* kf    = (float*)alloc((size_t)kTok * kD * 4);
  float* vf    = (float*)alloc((size_t)kTok * kD * 4);
  float* attnof= (float*)alloc((size_t)kTok * kD * 4);
  float* obuf  = (float*)alloc((size_t)kTok * kD * 4);
  float* x1f   = (float*)alloc((size_t)kTok * kD * 4);
  float* x2f   = (float*)alloc((size_t)kTok * kD * 4);
  float* meanAcc = (float*)alloc((size_t)kE * kB * kD * 4);
  float* srcf = (float*)alloc(kTok * 4);
  float* padf = (float*)alloc(kTok * 4);
  float* keepf = (float*)alloc(kTok * 4);
  float* denom = (float*)alloc(2 * 4);
  int* counts = (int*)alloc(256); int* fill = counts + 8;
  int* offsets = (int*)alloc(256);
  int* sel = (int*)alloc(kTok * 2 * 4);
  float* wsel = (float*)alloc(kTok * 2 * 4);
  int* aidxArr = (int*)alloc(2 * kTok * 4);
  int* slotArr = (int*)alloc(2 * kTok * 4);
  float* wgtArr = (float*)alloc(2 * kTok * 4);
  float* dots = (float*)alloc(256);
  int* dflag = (int*)alloc(256);

  auto g3 = [&](const void* A, const void* Bmat, float* C, int M, int N, int K,
                int lda, int ldb, int ldc, int bT, int aF, int bF,
                long long a0, long long a1, long long b0, long long b1,
                long long c0, long long c1, int zdiv, int zA, int zB, int zC,
                int nz, const void* bias) {
    G3P p;
    p.A = A; p.Bm = Bmat; p.C = C;
    p.a0 = a0; p.a1 = a1; p.b0 = b0; p.b1 = b1; p.c0 = c0; p.c1 = c1;
    p.zdiv = zdiv; p.zA = zA; p.zB = zB; p.zC = zC;
    p.lda = lda; p.ldb = ldb; p.ldc = ldc; p.M = M; p.N = N; p.K = K;
    p.bT = bT; p.aF = aF; p.bF = bF; p.dflag = dflag; p.bias = bias;
    dim3 grid(N / 64, M / 64, nz);
    gemm3_k<<<grid, dim3(256), 0, stream>>>(p);
  };

  hipMemsetAsync(counts, 0, 64, stream);
  hipMemsetAsync(meanAcc, 0, (size_t)kE * kB * kD * 4, stream);
  detect_k<<<1, 256, 0, stream>>>(x_in, dflag);
  maskprep_k<<<1, 256, 0, stream>>>(srcm, tgtm, midm, srcf, padf, keepf, denom);

  const long long SD = (long long)kS * kD;
  const long long SS = (long long)kS * kS;

  auto attention = [&](const void* qsrc, int qF, const void* ksrc, int kvF,
                       const void* wq, const void* wk, const void* wv,
                       const void* wo, const void* bo, const float* maskf) {
    g3(qsrc, wq, qf, kTok, kD, kD, kD, kD, kD, 0, qF, 1, 0,0,0,0,0,0, 1,0,0,0, 1, nullptr);
    g3(ksrc, wk, kf, kTok, kD, kD, kD, kD, kD, 0, kvF, 1, 0,0,0,0,0,0, 1,0,0,0, 1, nullptr);
    g3(ksrc, wv, vf, kTok, kD, kD, kD, kD, kD, 0, kvF, 1, 0,0,0,0,0,0, 1,0,0,0, 1, nullptr);
    for (int c = 0; c < 2; c++) {
      int zb = c * 16;
      g3(qf, kf, scFP, kS, kS, kDH, kD, kD, kS, 1, 2, 2,
         SD, 64, SD, 64, 0, SS, 16, zb, zb, 0, 16, nullptr);
      softmax_k<<<16 * kS, 256, 0, stream>>>(scFP, maskf, zb);
      g3(scFP, vf, attnof, kS, kDH, kS, kS, kD, kD, 0, 2, 2,
         0, SS, SD, 64, SD, 64, 16, 0, zb, zb, 16, nullptr);
    }
    g3(attnof, wo, obuf, kTok, kD, kD, kD, kD, kD, 0, 2, 1, 0,0,0,0,0,0, 1,0,0,0, 1, bo);
  };

  // ---- self attention ----
  attention(x_in, 1, x_in, 1, sa_wq, sa_wk, sa_wv, sa_wo, sa_bo, padf);
  ln_k<<<kTok, 256, 0, stream>>>(nullptr, x_in, dflag, 1, obuf, nullptr, ln1g, ln1b, x1f, nullptr);

  // ---- cross attention ----
  attention(x1f, 2, enc, 1, ca_wq, ca_wk, ca_wv, ca_wo, ca_bo, srcf);
  ln_k<<<kTok, 256, 0, stream>>>(x1f, nullptr, dflag, 0, obuf, nullptr, ln2g, ln2b, x2f, nullptr);

  // ---- MoE ----
  router_k<<<kTok / 4, 256, 0, stream>>>(x2f, gate_w, d_out, sel, wsel, counts, dflag);
  offsets_k<<<1, 64, 0, stream>>>(counts, offsets);
  place_k<<<kTok / 256, 256, 0, stream>>>(sel, wsel, offsets, fill, aidxArr, slotArr, wgtArr);
  moe13_k<<<dim3(kHID / 64, kTok / 64, kE), 256, 0, stream>>>(x2f, moe_w1, moe_w3, counts, offsets, aidxArr, Hbuf, dflag);
  w2_k<<<dim3(kD / 64, kTok / 64, kE), 256, 0, stream>>>(Hbuf, moe_w2, counts, offsets, aidxArr, slotArr, wgtArr, contrib, dflag);
  meanacc_k<<<dim3(kE, kD / 128, 16), 128, 0, stream>>>(counts, offsets, aidxArr, slotArr, keepf, contrib, meanAcc);
  dots_k<<<kE * kB, 256, 0, stream>>>(meanAcc, cls_w, denom, dots, dflag);
  final_logits_k<<<1, 64, 0, stream>>>(dots, cls_b, d_out, dflag);
  ln_k<<<kTok, 256, 0, stream>>>(x2f, nullptr, dflag, 0, contrib, contrib + (size_t)kTok * kD, ln3g, ln3b, nullptr, d_out);
}